// Round 6
// baseline (9761.536 us; speedup 1.0000x reference)
//
#include <hip/hip_runtime.h>
#include <math.h>

#define NCODES 16384
#define DIM    256
#define CH     256
#define HW     1024
#define MTOT   16384
#define OUT_ELEMS 4194304

#define BM 128          // rows per block
#define CT 256          // col tile
#define BK 8            // k chunk
#define NQ 4096         // cols per block (N split in 4 quarters)

// separately-rounded f32 multiply (blocks FMA contraction: numpy computes
// the product array first, then pairwise-sums it)
__device__ __forceinline__ float mulr(float a, float b) {
    float p = a * b;
    asm volatile("" : "+v"(p));
    return p;
}

// ---------------- kernel 1: codebook row norms, numpy pairwise order ----------------
__global__ __launch_bounds__(256) void k_cnorm(const float* __restrict__ cb,
                                               float* __restrict__ cnorm) {
    int row = blockIdx.x * 256 + threadIdx.x;
    const float* cp = cb + (size_t)row * DIM;
    float r0[8], r1[8];
    #pragma unroll
    for (int j = 0; j < 8; ++j) {
        float v0 = cp[j], v1 = cp[128 + j];
        r0[j] = mulr(v0, v0);
        r1[j] = mulr(v1, v1);
    }
    for (int i = 8; i < 128; i += 8) {
        #pragma unroll
        for (int j = 0; j < 8; ++j) {
            float v0 = cp[i + j], v1 = cp[128 + i + j];
            r0[j] += mulr(v0, v0);
            r1[j] += mulr(v1, v1);
        }
    }
    float s0 = ((r0[0] + r0[1]) + (r0[2] + r0[3])) + ((r0[4] + r0[5]) + (r0[6] + r0[7]));
    float s1 = ((r1[0] + r1[1]) + (r1[2] + r1[3])) + ((r1[4] + r1[5]) + (r1[6] + r1[7]));
    cnorm[row] = s0 + s1;
}

// ---------------- kernel 1b: z row norms (strided layout), same numpy order ----------
__global__ __launch_bounds__(256) void k_anorm(const float* __restrict__ z,
                                               float* __restrict__ anorm) {
    int m = blockIdx.x * 256 + threadIdx.x;
    int b = m / HW, hw = m % HW;
    const float* zp = z + (size_t)b * (CH * HW) + hw;
    float r0[8], r1[8];
    #pragma unroll
    for (int j = 0; j < 8; ++j) {
        float v0 = zp[(size_t)j * HW];
        float v1 = zp[(size_t)(128 + j) * HW];
        r0[j] = mulr(v0, v0);
        r1[j] = mulr(v1, v1);
    }
    for (int i = 8; i < 128; i += 8) {
        #pragma unroll
        for (int j = 0; j < 8; ++j) {
            float v0 = zp[(size_t)(i + j) * HW];
            float v1 = zp[(size_t)(128 + i + j) * HW];
            r0[j] += mulr(v0, v0);
            r1[j] += mulr(v1, v1);
        }
    }
    float s0 = ((r0[0] + r0[1]) + (r0[2] + r0[3])) + ((r0[4] + r0[5]) + (r0[6] + r0[7]));
    float s1 = ((r1[0] + r1[1]) + (r1[2] + r1[3])) + ((r1[4] + r1[5]) + (r1[6] + r1[7]));
    anorm[m] = s0 + s1;
}

// ---------------- kernel 2: GEMM (sequential-k f32 FMA, BLAS order) + argmin --------
// Each block: BM=128 rows x one N-quarter (4096 cols). TM=8 x TN=16 per thread.
// d(m,n) = fl( fl(A_m + B_n) - 2*P_mn ); per-quarter lexicographic (d,n) top-1.
// ONE 56 KB static LDS object (volatile-touched, cannot be DCE'd/shrunk):
// compile-time occupancy bound = 2 blocks/CU = 2 waves/SIMD -> 256-VGPR budget
// -> acc[8][16] stays in registers (no scratch spill).
__global__ __launch_bounds__(256, 2)
void k_argmin(const float* __restrict__ z,
              const float* __restrict__ cb,
              const float* __restrict__ cnorm,
              const float* __restrict__ anorm,
              float* __restrict__ pv,
              int* __restrict__ pi) {
    __shared__ float smem[14336];        // 57344 B total static LDS
    // carve-outs:
    //   lds_a: [2][BK][BM]  = 2048 floats  at smem + 0
    //   lds_b: [2][BK][CT]  = 4096 floats  at smem + 2048
    float* lds_a = smem;
    float* lds_b = smem + 2048;
    #define LDSA(buf, d, m) lds_a[((buf) * BK + (d)) * BM + (m)]
    #define LDSB(buf, d, n) lds_b[((buf) * BK + (d)) * CT + (n)]

    const int t  = threadIdx.x;
    if (t == 0) {                         // volatile touch: keeps full 56 KB allocated
        volatile float* vp = &smem[14335];
        *vp = 1.0f;
    }
    const int tx = t & 15;               // 16 col-groups
    const int ty = t >> 4;               // 16 row-groups (TM=8 rows each)
    const int mb   = (int)(blockIdx.x >> 2) * BM;
    const int quar = (int)(blockIdx.x & 3);
    const int colbase = quar * NQ;
    const int zb  = mb / HW;             // 128 | 1024: no batch straddle
    const int hw0 = mb % HW;
    const float* zbase = z + (size_t)zb * (CH * HW) + hw0;

    // staging roles
    const int sa_d = t >> 5;             // 0..7
    const int sa_m = (t & 31) * 4;       // 0..124

    float Am[8];
    #pragma unroll
    for (int i = 0; i < 8; ++i) Am[i] = anorm[mb + ty * 8 + i];

    float bv[8];
    int   bi[8];
    #pragma unroll
    for (int i = 0; i < 8; ++i) { bv[i] = INFINITY; bi[i] = 0x7fffffff; }

    for (int nt = 0; nt < NQ / CT; ++nt) {
        const int n0 = colbase + nt * CT;
        const float* crow = cb + (size_t)(n0 + t) * DIM;

        float acc[8][16];
        #pragma unroll
        for (int i = 0; i < 8; ++i)
            #pragma unroll
            for (int j = 0; j < 16; ++j) acc[i][j] = 0.f;

        // prologue: chunk 0 into buf 0
        float4 a0 = *reinterpret_cast<const float4*>(zbase + (size_t)sa_d * HW + sa_m);
        float4 u0 = *reinterpret_cast<const float4*>(crow + 0);
        float4 u1 = *reinterpret_cast<const float4*>(crow + 4);
        __syncthreads();  // previous tile's buffer reads complete
        *reinterpret_cast<float4*>(&LDSA(0, sa_d, sa_m)) = a0;
        LDSB(0, 0, t) = u0.x; LDSB(0, 1, t) = u0.y; LDSB(0, 2, t) = u0.z; LDSB(0, 3, t) = u0.w;
        LDSB(0, 4, t) = u1.x; LDSB(0, 5, t) = u1.y; LDSB(0, 6, t) = u1.z; LDSB(0, 7, t) = u1.w;

        for (int kc = 0; kc < DIM / BK; ++kc) {
            const int cur = kc & 1;
            __syncthreads();  // buf[cur] visible; buf[cur^1] free to overwrite

            float4 na, nb0, nb1;
            if (kc < DIM / BK - 1) {
                na  = *reinterpret_cast<const float4*>(zbase + (size_t)((kc + 1) * BK + sa_d) * HW + sa_m);
                nb0 = *reinterpret_cast<const float4*>(crow + (kc + 1) * BK);
                nb1 = *reinterpret_cast<const float4*>(crow + (kc + 1) * BK + 4);
            }

            #pragma unroll
            for (int kk = 0; kk < BK; ++kk) {
                float af[8];
                *reinterpret_cast<float4*>(&af[0]) = *reinterpret_cast<const float4*>(&LDSA(cur, kk, ty * 8));
                *reinterpret_cast<float4*>(&af[4]) = *reinterpret_cast<const float4*>(&LDSA(cur, kk, ty * 8 + 4));
                float bf[16];
                *reinterpret_cast<float4*>(&bf[0])  = *reinterpret_cast<const float4*>(&LDSB(cur, kk, tx * 4));
                *reinterpret_cast<float4*>(&bf[4])  = *reinterpret_cast<const float4*>(&LDSB(cur, kk, 64 + tx * 4));
                *reinterpret_cast<float4*>(&bf[8])  = *reinterpret_cast<const float4*>(&LDSB(cur, kk, 128 + tx * 4));
                *reinterpret_cast<float4*>(&bf[12]) = *reinterpret_cast<const float4*>(&LDSB(cur, kk, 192 + tx * 4));
                #pragma unroll
                for (int i = 0; i < 8; ++i)
                    #pragma unroll
                    for (int j = 0; j < 16; ++j)
                        acc[i][j] = fmaf(af[i], bf[j], acc[i][j]);  // sequential k: matches sgemm
            }

            if (kc < DIM / BK - 1) {
                const int nb = cur ^ 1;
                *reinterpret_cast<float4*>(&LDSA(nb, sa_d, sa_m)) = na;
                LDSB(nb, 0, t) = nb0.x; LDSB(nb, 1, t) = nb0.y; LDSB(nb, 2, t) = nb0.z; LDSB(nb, 3, t) = nb0.w;
                LDSB(nb, 4, t) = nb1.x; LDSB(nb, 5, t) = nb1.y; LDSB(nb, 6, t) = nb1.z; LDSB(nb, 7, t) = nb1.w;
            }
        }

        // epilogue: d = fl(fl(Am+Bn) - 2*P); lexicographic (d, n) running min
        float cnv[16];
        #pragma unroll
        for (int jb = 0; jb < 4; ++jb) {
            float4 c4 = *reinterpret_cast<const float4*>(cnorm + n0 + jb * 64 + tx * 4);
            cnv[jb * 4 + 0] = c4.x; cnv[jb * 4 + 1] = c4.y;
            cnv[jb * 4 + 2] = c4.z; cnv[jb * 4 + 3] = c4.w;
        }
        #pragma unroll
        for (int i = 0; i < 8; ++i)
            #pragma unroll
            for (int jb = 0; jb < 4; ++jb)
                #pragma unroll
                for (int jj = 0; jj < 4; ++jj) {
                    float t1 = Am[i] + cnv[jb * 4 + jj];
                    float dd = t1 - 2.0f * acc[i][jb * 4 + jj];
                    int n = n0 + jb * 64 + tx * 4 + jj;
                    if (dd < bv[i] || (dd == bv[i] && n < bi[i])) { bv[i] = dd; bi[i] = n; }
                }
    }

    // reduce across the 16 tx lanes (lane bits 0..3: stays within wave & ty group)
    #pragma unroll
    for (int i = 0; i < 8; ++i) {
        #pragma unroll
        for (int o = 1; o < 16; o <<= 1) {
            float ov = __shfl_xor(bv[i], o, 64);
            int   oi = __shfl_xor(bi[i], o, 64);
            if (ov < bv[i] || (ov == bv[i] && oi < bi[i])) { bv[i] = ov; bi[i] = oi; }
        }
        if (tx == 0) {
            int row = mb + ty * 8 + i;
            pv[quar * MTOT + row] = bv[i];
            pi[quar * MTOT + row] = bi[i];
        }
    }
    #undef LDSA
    #undef LDSB
}

// ---------------- kernel 2b: combine the four N-quarters ----------------
__global__ __launch_bounds__(256) void k_combine(const float* __restrict__ pv,
                                                 const int* __restrict__ pi,
                                                 int* __restrict__ idxi,
                                                 float* __restrict__ idxf) {
    int m = blockIdx.x * 256 + threadIdx.x;
    float v = pv[m];
    int   i = pi[m];
    #pragma unroll
    for (int q = 1; q < 4; ++q) {
        float vq = pv[q * MTOT + m];
        int   iq = pi[q * MTOT + m];
        if (vq < v || (vq == v && iq < i)) { v = vq; i = iq; }
    }
    idxi[m] = i;
    idxf[m] = (float)i;
}

// ---------------- kernel 3: gather z_q, write out, accumulate loss ----------------
__global__ __launch_bounds__(256) void k_gather(const float* __restrict__ z,
                                                const float* __restrict__ cb,
                                                const int* __restrict__ idx,
                                                float* __restrict__ out,
                                                double* __restrict__ lacc) {
    int t = threadIdx.x;
    int hwi = t & 63, cg = t >> 6;
    int m = blockIdx.x * 64 + hwi;
    int b = m / HW, hw = m % HW;
    const float* erow = cb + (size_t)idx[m] * DIM;
    size_t zoff = (size_t)b * (CH * HW) + hw;
    double ls = 0.0;
    #pragma unroll 4
    for (int cc = 0; cc < 64; ++cc) {
        int c = cg * 64 + cc;
        float e  = erow[c];
        float zv = z[zoff + (size_t)c * HW];
        out[zoff + (size_t)c * HW] = e;
        float d = e - zv;
        ls += (double)d * (double)d;
    }
    #pragma unroll
    for (int o = 32; o; o >>= 1) ls += __shfl_xor(ls, o, 64);
    __shared__ double wsum[4];
    if ((t & 63) == 0) wsum[t >> 6] = ls;
    __syncthreads();
    if (t == 0) atomicAdd(lacc, wsum[0] + wsum[1] + wsum[2] + wsum[3]);
}

__global__ void k_final(const double* __restrict__ lacc, float* __restrict__ loss) {
    *loss = (float)(*lacc * (1.25 / (double)OUT_ELEMS));
}

extern "C" void kernel_launch(void* const* d_in, const int* in_sizes, int n_in,
                              void* d_out, int out_size, void* d_ws, size_t ws_size,
                              hipStream_t stream) {
    const float* z  = (const float*)d_in[0];
    const float* cb = (const float*)d_in[1];
    float* out      = (float*)d_out;
    float* loss_out = out + OUT_ELEMS;
    float* idxf     = out + OUT_ELEMS + 1;

    float*  cnorm = (float*)d_ws;                                  // 64 KB
    float*  anorm = (float*)((char*)d_ws + 65536);                 // 64 KB
    int*    idxi  = (int*)((char*)d_ws + 131072);                  // 64 KB
    float*  pv    = (float*)((char*)d_ws + 196608);                // 256 KB
    int*    pi    = (int*)((char*)d_ws + 458752);                  // 256 KB
    double* lacc  = (double*)((char*)d_ws + 720896);               // 8 B

    hipMemsetAsync(lacc, 0, sizeof(double), stream);

    k_cnorm  <<<NCODES / 256,    256, 0, stream>>>(cb, cnorm);
    k_anorm  <<<MTOT / 256,      256, 0, stream>>>(z, anorm);
    k_argmin <<<(MTOT / BM) * 4, 256, 0, stream>>>(z, cb, cnorm, anorm, pv, pi);
    k_combine<<<MTOT / 256,      256, 0, stream>>>(pv, pi, idxi, idxf);
    k_gather <<<MTOT / 64,       256, 0, stream>>>(z, cb, idxi, out, lacc);
    k_final  <<<1, 1, 0, stream>>>(lacc, loss_out);
}

// Round 7
// 2740.379 us; speedup vs baseline: 3.5621x; 3.5621x over previous
//
#include <hip/hip_runtime.h>
#include <math.h>

#define NCODES 16384
#define DIM    256
#define CH     256
#define HW     1024
#define MTOT   16384
#define OUT_ELEMS 4194304

// separately-rounded f32 multiply (blocks FMA contraction: numpy computes
// the product array first, then pairwise-sums it)
__device__ __forceinline__ float mulr(float a, float b) {
    float p = a * b;
    asm volatile("" : "+v"(p));
    return p;
}

// ---------------- kernel 1: codebook row norms, numpy pairwise order ----------------
__global__ __launch_bounds__(256) void k_cnorm(const float* __restrict__ cb,
                                               float* __restrict__ cnorm) {
    int row = blockIdx.x * 256 + threadIdx.x;
    const float* cp = cb + (size_t)row * DIM;
    float r0[8], r1[8];
    #pragma unroll
    for (int j = 0; j < 8; ++j) {
        float v0 = cp[j], v1 = cp[128 + j];
        r0[j] = mulr(v0, v0);
        r1[j] = mulr(v1, v1);
    }
    for (int i = 8; i < 128; i += 8) {
        #pragma unroll
        for (int j = 0; j < 8; ++j) {
            float v0 = cp[i + j], v1 = cp[128 + i + j];
            r0[j] += mulr(v0, v0);
            r1[j] += mulr(v1, v1);
        }
    }
    float s0 = ((r0[0] + r0[1]) + (r0[2] + r0[3])) + ((r0[4] + r0[5]) + (r0[6] + r0[7]));
    float s1 = ((r1[0] + r1[1]) + (r1[2] + r1[3])) + ((r1[4] + r1[5]) + (r1[6] + r1[7]));
    cnorm[row] = s0 + s1;
}

// ---------------- kernel 1b: z row norms (strided layout), same numpy order ----------
__global__ __launch_bounds__(256) void k_anorm(const float* __restrict__ z,
                                               float* __restrict__ anorm) {
    int m = blockIdx.x * 256 + threadIdx.x;
    int b = m / HW, hw = m % HW;
    const float* zp = z + (size_t)b * (CH * HW) + hw;
    float r0[8], r1[8];
    #pragma unroll
    for (int j = 0; j < 8; ++j) {
        float v0 = zp[(size_t)j * HW];
        float v1 = zp[(size_t)(128 + j) * HW];
        r0[j] = mulr(v0, v0);
        r1[j] = mulr(v1, v1);
    }
    for (int i = 8; i < 128; i += 8) {
        #pragma unroll
        for (int j = 0; j < 8; ++j) {
            float v0 = zp[(size_t)(i + j) * HW];
            float v1 = zp[(size_t)(128 + i + j) * HW];
            r0[j] += mulr(v0, v0);
            r1[j] += mulr(v1, v1);
        }
    }
    float s0 = ((r0[0] + r0[1]) + (r0[2] + r0[3])) + ((r0[4] + r0[5]) + (r0[6] + r0[7]));
    float s1 = ((r1[0] + r1[1]) + (r1[2] + r1[3])) + ((r1[4] + r1[5]) + (r1[6] + r1[7]));
    anorm[m] = s0 + s1;
}

// ---------------- kernel 1c: transpose codebook to k-major bT[k][n] ----------------
__global__ __launch_bounds__(256) void k_btrans(const float* __restrict__ cb,
                                                float* __restrict__ bT) {
    __shared__ float tile[64][65];
    const int t  = threadIdx.x;
    const int nb = (int)(blockIdx.x & 255) * 64;
    const int kb = (int)(blockIdx.x >> 8) * 64;
    const int k4 = (t & 15) * 4;
    const int nn = t >> 4;
    #pragma unroll
    for (int p = 0; p < 4; ++p) {
        int n = p * 16 + nn;
        float4 v = *reinterpret_cast<const float4*>(cb + (size_t)(nb + n) * DIM + kb + k4);
        tile[n][k4 + 0] = v.x; tile[n][k4 + 1] = v.y;
        tile[n][k4 + 2] = v.z; tile[n][k4 + 3] = v.w;
    }
    __syncthreads();
    const int n4 = (t & 15) * 4;
    const int kk = t >> 4;
    #pragma unroll
    for (int p = 0; p < 4; ++p) {
        int k = p * 16 + kk;
        float4 o;
        o.x = tile[n4 + 0][k]; o.y = tile[n4 + 1][k];
        o.z = tile[n4 + 2][k]; o.w = tile[n4 + 3][k];
        *reinterpret_cast<float4*>(bT + (size_t)(kb + k) * NCODES + nb + n4) = o;
    }
}

// ---------------- kernel 2: GEMM-argmin, lane=row, B via wave-uniform scalar loads --
// Block: 64 rows (lane = row), 4 waves x 2048-col strips, one N-half per block.
// Per (m,n): acc = sequential-k f32 FMA chain (matches sgemm); d = fl(Am+Bn)-2*acc.
// Ascending-n scan with strict < keeps numpy's first-occurrence argmin.
__global__ __launch_bounds__(256)
void k_argmin(const float* __restrict__ z,
              const float* __restrict__ bT,
              const float* __restrict__ cnorm,
              const float* __restrict__ anorm,
              float* __restrict__ pv,
              int* __restrict__ pi) {
    __shared__ float lA[16384];          // [kq 0..63][m 0..63][kr 0..3] = 64 KB
    const int t    = threadIdx.x;
    const int lane = t & 63;
    const int w    = __builtin_amdgcn_readfirstlane(t >> 6);
    const int mb   = (int)(blockIdx.x >> 1) * 64;
    const int h    = (int)(blockIdx.x & 1);

    // ---- stage A tile: 64 rows x 256 dims, coalesced global reads ----
    const int zb = mb / HW, hw0 = mb % HW;
    const float* zbase = z + (size_t)zb * (CH * HW) + hw0;
    const int sd = t >> 4;               // 0..15
    const int sm = (t & 15) * 4;         // 0..60
    #pragma unroll
    for (int p = 0; p < 16; ++p) {
        int d = p * 16 + sd;
        float4 v = *reinterpret_cast<const float4*>(zbase + (size_t)d * HW + sm);
        int base = (d >> 2) * 256 + (d & 3);
        lA[base + (sm + 0) * 4] = v.x;
        lA[base + (sm + 1) * 4] = v.y;
        lA[base + (sm + 2) * 4] = v.z;
        lA[base + (sm + 3) * 4] = v.w;
    }
    float Am = anorm[mb + lane];
    __syncthreads();

    float bvv = INFINITY;
    int   bii = 0x7fffffff;
    const int nwbase = h * 8192 + w * 2048;

    for (int cg = 0; cg < 128; ++cg) {
        const int n0 = nwbase + cg * 16;      // wave-uniform
        const float* bp = bT + n0;
        float acc[16];
        #pragma unroll
        for (int j = 0; j < 16; ++j) acc[j] = 0.f;

        for (int kq = 0; kq < 64; ++kq) {
            float4 a4 = *reinterpret_cast<const float4*>(&lA[kq * 256 + lane * 4]);
            #pragma unroll
            for (int kk = 0; kk < 4; ++kk) {
                const float* bk = bp + (size_t)(kq * 4 + kk) * NCODES;  // uniform -> s_load
                float4 b0 = *reinterpret_cast<const float4*>(bk + 0);
                float4 b1 = *reinterpret_cast<const float4*>(bk + 4);
                float4 b2 = *reinterpret_cast<const float4*>(bk + 8);
                float4 b3 = *reinterpret_cast<const float4*>(bk + 12);
                float a = (kk == 0) ? a4.x : (kk == 1) ? a4.y : (kk == 2) ? a4.z : a4.w;
                acc[0]  = fmaf(a, b0.x, acc[0]);  acc[1]  = fmaf(a, b0.y, acc[1]);
                acc[2]  = fmaf(a, b0.z, acc[2]);  acc[3]  = fmaf(a, b0.w, acc[3]);
                acc[4]  = fmaf(a, b1.x, acc[4]);  acc[5]  = fmaf(a, b1.y, acc[5]);
                acc[6]  = fmaf(a, b1.z, acc[6]);  acc[7]  = fmaf(a, b1.w, acc[7]);
                acc[8]  = fmaf(a, b2.x, acc[8]);  acc[9]  = fmaf(a, b2.y, acc[9]);
                acc[10] = fmaf(a, b2.z, acc[10]); acc[11] = fmaf(a, b2.w, acc[11]);
                acc[12] = fmaf(a, b3.x, acc[12]); acc[13] = fmaf(a, b3.y, acc[13]);
                acc[14] = fmaf(a, b3.z, acc[14]); acc[15] = fmaf(a, b3.w, acc[15]);
            }
        }

        float4 c0 = *reinterpret_cast<const float4*>(cnorm + n0);
        float4 c1 = *reinterpret_cast<const float4*>(cnorm + n0 + 4);
        float4 c2 = *reinterpret_cast<const float4*>(cnorm + n0 + 8);
        float4 c3 = *reinterpret_cast<const float4*>(cnorm + n0 + 12);
        float cn[16] = {c0.x, c0.y, c0.z, c0.w, c1.x, c1.y, c1.z, c1.w,
                        c2.x, c2.y, c2.z, c2.w, c3.x, c3.y, c3.z, c3.w};
        #pragma unroll
        for (int j = 0; j < 16; ++j) {
            float t1 = Am + cn[j];                 // f32 round
            float dd = fmaf(-2.f, acc[j], t1);     // fl(t1 - 2*P), single rounding
            if (dd < bvv) { bvv = dd; bii = n0 + j; }
        }
    }

    const int slot = h * 4 + w;                    // slots ordered by ascending n range
    pv[slot * MTOT + mb + lane] = bvv;
    pi[slot * MTOT + mb + lane] = bii;
}

// ---------------- kernel 2b: merge the 8 ordered column strips ----------------
__global__ __launch_bounds__(256) void k_combine(const float* __restrict__ pv,
                                                 const int* __restrict__ pi,
                                                 int* __restrict__ idxi,
                                                 float* __restrict__ idxf) {
    int m = blockIdx.x * 256 + threadIdx.x;
    float v = pv[m];
    int   i = pi[m];
    #pragma unroll
    for (int s = 1; s < 8; ++s) {
        float vs = pv[s * MTOT + m];
        int   is = pi[s * MTOT + m];
        if (vs < v) { v = vs; i = is; }   // strict <: earlier slot = lower n wins ties
    }
    idxi[m] = i;
    idxf[m] = (float)i;
}

// ---------------- kernel 3: gather z_q, write out, accumulate loss ----------------
__global__ __launch_bounds__(256) void k_gather(const float* __restrict__ z,
                                                const float* __restrict__ cb,
                                                const int* __restrict__ idx,
                                                float* __restrict__ out,
                                                double* __restrict__ lacc) {
    int t = threadIdx.x;
    int hwi = t & 63, cg = t >> 6;
    int m = blockIdx.x * 64 + hwi;
    int b = m / HW, hw = m % HW;
    const float* erow = cb + (size_t)idx[m] * DIM;
    size_t zoff = (size_t)b * (CH * HW) + hw;
    double ls = 0.0;
    #pragma unroll 4
    for (int cc = 0; cc < 64; ++cc) {
        int c = cg * 64 + cc;
        float e  = erow[c];
        float zv = z[zoff + (size_t)c * HW];
        out[zoff + (size_t)c * HW] = e;
        float d = e - zv;
        ls += (double)d * (double)d;
    }
    #pragma unroll
    for (int o = 32; o; o >>= 1) ls += __shfl_xor(ls, o, 64);
    __shared__ double wsum[4];
    if ((t & 63) == 0) wsum[t >> 6] = ls;
    __syncthreads();
    if (t == 0) atomicAdd(lacc, wsum[0] + wsum[1] + wsum[2] + wsum[3]);
}

__global__ void k_final(const double* __restrict__ lacc, float* __restrict__ loss) {
    *loss = (float)(*lacc * (1.25 / (double)OUT_ELEMS));
}

extern "C" void kernel_launch(void* const* d_in, const int* in_sizes, int n_in,
                              void* d_out, int out_size, void* d_ws, size_t ws_size,
                              hipStream_t stream) {
    const float* z  = (const float*)d_in[0];
    const float* cb = (const float*)d_in[1];
    float* out      = (float*)d_out;
    float* loss_out = out + OUT_ELEMS;
    float* idxf     = out + OUT_ELEMS + 1;

    // bT (16 MB) lives in the d_out tensor region; k_gather overwrites it later.
    float* bT = out;

    float*  cnorm = (float*)d_ws;                                  // 64 KB
    float*  anorm = (float*)((char*)d_ws + 65536);                 // 64 KB
    int*    idxi  = (int*)((char*)d_ws + 131072);                  // 64 KB
    float*  pv    = (float*)((char*)d_ws + 196608);                // 512 KB (8 slots)
    int*    pi    = (int*)((char*)d_ws + 720896);                  // 512 KB
    double* lacc  = (double*)((char*)d_ws + 1245184);              // 8 B

    hipMemsetAsync(lacc, 0, sizeof(double), stream);

    k_cnorm  <<<NCODES / 256, 256, 0, stream>>>(cb, cnorm);
    k_anorm  <<<MTOT / 256,   256, 0, stream>>>(z, anorm);
    k_btrans <<<1024,         256, 0, stream>>>(cb, bT);
    k_argmin <<<(MTOT / 64) * 2, 256, 0, stream>>>(z, bT, cnorm, anorm, pv, pi);
    k_combine<<<MTOT / 256,   256, 0, stream>>>(pv, pi, idxi, idxf);
    k_gather <<<MTOT / 64,    256, 0, stream>>>(z, cb, idxi, out, lacc);
    k_final  <<<1, 1, 0, stream>>>(lacc, loss_out);
}

// Round 8
// 2206.227 us; speedup vs baseline: 4.4245x; 1.2421x over previous
//
#include <hip/hip_runtime.h>
#include <math.h>

#define NCODES 16384
#define DIM    256
#define CH     256
#define HW     1024
#define MTOT   16384
#define OUT_ELEMS 4194304

// separately-rounded f32 multiply (blocks FMA contraction: numpy computes
// the product array first, then pairwise-sums it)
__device__ __forceinline__ float mulr(float a, float b) {
    float p = a * b;
    asm volatile("" : "+v"(p));
    return p;
}

// ---------------- kernel 1: codebook row norms, numpy pairwise order ----------------
__global__ __launch_bounds__(256) void k_cnorm(const float* __restrict__ cb,
                                               float* __restrict__ cnorm) {
    int row = blockIdx.x * 256 + threadIdx.x;
    const float* cp = cb + (size_t)row * DIM;
    float r0[8], r1[8];
    #pragma unroll
    for (int j = 0; j < 8; ++j) {
        float v0 = cp[j], v1 = cp[128 + j];
        r0[j] = mulr(v0, v0);
        r1[j] = mulr(v1, v1);
    }
    for (int i = 8; i < 128; i += 8) {
        #pragma unroll
        for (int j = 0; j < 8; ++j) {
            float v0 = cp[i + j], v1 = cp[128 + i + j];
            r0[j] += mulr(v0, v0);
            r1[j] += mulr(v1, v1);
        }
    }
    float s0 = ((r0[0] + r0[1]) + (r0[2] + r0[3])) + ((r0[4] + r0[5]) + (r0[6] + r0[7]));
    float s1 = ((r1[0] + r1[1]) + (r1[2] + r1[3])) + ((r1[4] + r1[5]) + (r1[6] + r1[7]));
    cnorm[row] = s0 + s1;
}

// ---------------- kernel 1b: z row norms (strided layout), same numpy order ----------
__global__ __launch_bounds__(256) void k_anorm(const float* __restrict__ z,
                                               float* __restrict__ anorm) {
    int m = blockIdx.x * 256 + threadIdx.x;
    int b = m / HW, hw = m % HW;
    const float* zp = z + (size_t)b * (CH * HW) + hw;
    float r0[8], r1[8];
    #pragma unroll
    for (int j = 0; j < 8; ++j) {
        float v0 = zp[(size_t)j * HW];
        float v1 = zp[(size_t)(128 + j) * HW];
        r0[j] = mulr(v0, v0);
        r1[j] = mulr(v1, v1);
    }
    for (int i = 8; i < 128; i += 8) {
        #pragma unroll
        for (int j = 0; j < 8; ++j) {
            float v0 = zp[(size_t)(i + j) * HW];
            float v1 = zp[(size_t)(128 + i + j) * HW];
            r0[j] += mulr(v0, v0);
            r1[j] += mulr(v1, v1);
        }
    }
    float s0 = ((r0[0] + r0[1]) + (r0[2] + r0[3])) + ((r0[4] + r0[5]) + (r0[6] + r0[7]));
    float s1 = ((r1[0] + r1[1]) + (r1[2] + r1[3])) + ((r1[4] + r1[5]) + (r1[6] + r1[7]));
    anorm[m] = s0 + s1;
}

// ---------------- kernel 1c: transpose codebook to k-major bT[k][n] ----------------
__global__ __launch_bounds__(256) void k_btrans(const float* __restrict__ cb,
                                                float* __restrict__ bT) {
    __shared__ float tile[64][65];
    const int t  = threadIdx.x;
    const int nb = (int)(blockIdx.x & 255) * 64;
    const int kb = (int)(blockIdx.x >> 8) * 64;
    const int k4 = (t & 15) * 4;
    const int nn = t >> 4;
    #pragma unroll
    for (int p = 0; p < 4; ++p) {
        int n = p * 16 + nn;
        float4 v = *reinterpret_cast<const float4*>(cb + (size_t)(nb + n) * DIM + kb + k4);
        tile[n][k4 + 0] = v.x; tile[n][k4 + 1] = v.y;
        tile[n][k4 + 2] = v.z; tile[n][k4 + 3] = v.w;
    }
    __syncthreads();
    const int n4 = (t & 15) * 4;
    const int kk = t >> 4;
    #pragma unroll
    for (int p = 0; p < 4; ++p) {
        int k = p * 16 + kk;
        float4 o;
        o.x = tile[n4 + 0][k]; o.y = tile[n4 + 1][k];
        o.z = tile[n4 + 2][k]; o.w = tile[n4 + 3][k];
        *reinterpret_cast<float4*>(bT + (size_t)(kb + k) * NCODES + nb + n4) = o;
    }
}

// ---------------- kernel 2: GEMM-argmin, lane=row, B via wave-uniform scalar loads --
// Block: 512 threads = 8 waves. 64 rows (lane = row), each wave a 1024-col strip of
// one N-half. Per (m,n): acc = sequential-k f32 FMA chain (sgemm order);
// d = fl(fl(Am+Bn) - 2*acc). Ascending-n scan, strict < => numpy first-occurrence.
__global__ __launch_bounds__(512)
void k_argmin(const float* __restrict__ z,
              const float* __restrict__ bT,
              const float* __restrict__ cnorm,
              const float* __restrict__ anorm,
              float* __restrict__ pv,
              int* __restrict__ pi) {
    __shared__ float lA[16384];          // [kq 0..63][m 0..63][kr 0..3] = 64 KB
    const int t    = threadIdx.x;
    const int lane = t & 63;
    const int w    = __builtin_amdgcn_readfirstlane(t >> 6);   // 0..7
    const int mb   = (int)(blockIdx.x >> 1) * 64;
    const int h    = (int)(blockIdx.x & 1);

    // ---- stage A tile: 64 rows x 256 dims, coalesced global reads ----
    const int zb = mb / HW, hw0 = mb % HW;
    const float* zbase = z + (size_t)zb * (CH * HW) + hw0;
    const int sd = t >> 4;               // 0..31
    const int sm = (t & 15) * 4;         // 0..60
    #pragma unroll
    for (int p = 0; p < 8; ++p) {
        int d = p * 32 + sd;
        float4 v = *reinterpret_cast<const float4*>(zbase + (size_t)d * HW + sm);
        int base = (d >> 2) * 256 + (d & 3);
        lA[base + (sm + 0) * 4] = v.x;
        lA[base + (sm + 1) * 4] = v.y;
        lA[base + (sm + 2) * 4] = v.z;
        lA[base + (sm + 3) * 4] = v.w;
    }
    float Am = anorm[mb + lane];
    __syncthreads();

    float bvv = INFINITY;
    int   bii = 0x7fffffff;
    const int nwbase = h * 8192 + w * 1024;

    for (int cg = 0; cg < 64; ++cg) {
        const int n0 = nwbase + cg * 16;      // wave-uniform
        const float* bp = bT + n0;
        float acc[16];
        #pragma unroll
        for (int j = 0; j < 16; ++j) acc[j] = 0.f;

        float4 a4 = *reinterpret_cast<const float4*>(&lA[lane * 4]);   // kq = 0
        for (int kq = 0; kq < 64; ++kq) {
            float4 a4n = *reinterpret_cast<const float4*>(&lA[(((kq + 1) & 63) * 256) + lane * 4]);
            #pragma unroll
            for (int kk = 0; kk < 4; ++kk) {
                const float* bk = bp + (size_t)(kq * 4 + kk) * NCODES;  // uniform -> s_load
                float4 b0 = *reinterpret_cast<const float4*>(bk + 0);
                float4 b1 = *reinterpret_cast<const float4*>(bk + 4);
                float4 b2 = *reinterpret_cast<const float4*>(bk + 8);
                float4 b3 = *reinterpret_cast<const float4*>(bk + 12);
                float a = (kk == 0) ? a4.x : (kk == 1) ? a4.y : (kk == 2) ? a4.z : a4.w;
                acc[0]  = fmaf(a, b0.x, acc[0]);  acc[1]  = fmaf(a, b0.y, acc[1]);
                acc[2]  = fmaf(a, b0.z, acc[2]);  acc[3]  = fmaf(a, b0.w, acc[3]);
                acc[4]  = fmaf(a, b1.x, acc[4]);  acc[5]  = fmaf(a, b1.y, acc[5]);
                acc[6]  = fmaf(a, b1.z, acc[6]);  acc[7]  = fmaf(a, b1.w, acc[7]);
                acc[8]  = fmaf(a, b2.x, acc[8]);  acc[9]  = fmaf(a, b2.y, acc[9]);
                acc[10] = fmaf(a, b2.z, acc[10]); acc[11] = fmaf(a, b2.w, acc[11]);
                acc[12] = fmaf(a, b3.x, acc[12]); acc[13] = fmaf(a, b3.y, acc[13]);
                acc[14] = fmaf(a, b3.z, acc[14]); acc[15] = fmaf(a, b3.w, acc[15]);
            }
            a4 = a4n;
        }

        float4 c0 = *reinterpret_cast<const float4*>(cnorm + n0);
        float4 c1 = *reinterpret_cast<const float4*>(cnorm + n0 + 4);
        float4 c2 = *reinterpret_cast<const float4*>(cnorm + n0 + 8);
        float4 c3 = *reinterpret_cast<const float4*>(cnorm + n0 + 12);
        float cn[16] = {c0.x, c0.y, c0.z, c0.w, c1.x, c1.y, c1.z, c1.w,
                        c2.x, c2.y, c2.z, c2.w, c3.x, c3.y, c3.z, c3.w};
        #pragma unroll
        for (int j = 0; j < 16; ++j) {
            float t1 = Am + cn[j];                 // f32 round
            float dd = fmaf(-2.f, acc[j], t1);     // fl(t1 - 2*P), single rounding
            if (dd < bvv) { bvv = dd; bii = n0 + j; }
        }
    }

    // ---- in-block ordered reduce across the 8 waves (ascending n strips) ----
    __syncthreads();                      // all waves done reading lA
    float* cv = lA;                       // [8][64] candidate values
    int*   ci = (int*)(lA + 512);         // [8][64] candidate indices
    cv[w * 64 + lane] = bvv;
    ci[w * 64 + lane] = bii;
    __syncthreads();
    if (t < 64) {
        float v = cv[t];
        int   i = ci[t];
        #pragma unroll
        for (int s = 1; s < 8; ++s) {
            float vs = cv[s * 64 + t];
            int   is = ci[s * 64 + t];
            if (vs < v) { v = vs; i = is; }   // strict <: lower strip wins ties
        }
        pv[h * MTOT + mb + t] = v;
        pi[h * MTOT + mb + t] = i;
    }
}

// ---------------- kernel 2b: merge the two ordered N-halves ----------------
__global__ __launch_bounds__(256) void k_combine(const float* __restrict__ pv,
                                                 const int* __restrict__ pi,
                                                 int* __restrict__ idxi,
                                                 float* __restrict__ idxf) {
    int m = blockIdx.x * 256 + threadIdx.x;
    float v = pv[m];
    int   i = pi[m];
    float v1 = pv[MTOT + m];
    int   i1 = pi[MTOT + m];
    if (v1 < v) { v = v1; i = i1; }        // strict <: lower half wins ties
    idxi[m] = i;
    idxf[m] = (float)i;
}

// ---------------- kernel 3: gather z_q, write out, accumulate loss ----------------
__global__ __launch_bounds__(256) void k_gather(const float* __restrict__ z,
                                                const float* __restrict__ cb,
                                                const int* __restrict__ idx,
                                                float* __restrict__ out,
                                                double* __restrict__ lacc) {
    int t = threadIdx.x;
    int hwi = t & 63, cg = t >> 6;
    int m = blockIdx.x * 64 + hwi;
    int b = m / HW, hw = m % HW;
    const float* erow = cb + (size_t)idx[m] * DIM;
    size_t zoff = (size_t)b * (CH * HW) + hw;
    double ls = 0.0;
    #pragma unroll 4
    for (int cc = 0; cc < 64; ++cc) {
        int c = cg * 64 + cc;
        float e  = erow[c];
        float zv = z[zoff + (size_t)c * HW];
        out[zoff + (size_t)c * HW] = e;
        float d = e - zv;
        ls += (double)d * (double)d;
    }
    #pragma unroll
    for (int o = 32; o; o >>= 1) ls += __shfl_xor(ls, o, 64);
    __shared__ double wsum[4];
    if ((t & 63) == 0) wsum[t >> 6] = ls;
    __syncthreads();
    if (t == 0) atomicAdd(lacc, wsum[0] + wsum[1] + wsum[2] + wsum[3]);
}

__global__ void k_final(const double* __restrict__ lacc, float* __restrict__ loss) {
    *loss = (float)(*lacc * (1.25 / (double)OUT_ELEMS));
}

extern "C" void kernel_launch(void* const* d_in, const int* in_sizes, int n_in,
                              void* d_out, int out_size, void* d_ws, size_t ws_size,
                              hipStream_t stream) {
    const float* z  = (const float*)d_in[0];
    const float* cb = (const float*)d_in[1];
    float* out      = (float*)d_out;
    float* loss_out = out + OUT_ELEMS;
    float* idxf     = out + OUT_ELEMS + 1;

    // bT (16 MB) lives in the d_out tensor region; k_gather overwrites it later.
    float* bT = out;

    float*  cnorm = (float*)d_ws;                                  // 64 KB
    float*  anorm = (float*)((char*)d_ws + 65536);                 // 64 KB
    int*    idxi  = (int*)((char*)d_ws + 131072);                  // 64 KB
    float*  pv    = (float*)((char*)d_ws + 196608);                // 128 KB (2 slots)
    int*    pi    = (int*)((char*)d_ws + 327680);                  // 128 KB
    double* lacc  = (double*)((char*)d_ws + 458752);               // 8 B

    hipMemsetAsync(lacc, 0, sizeof(double), stream);

    k_cnorm  <<<NCODES / 256, 256, 0, stream>>>(cb, cnorm);
    k_anorm  <<<MTOT / 256,   256, 0, stream>>>(z, anorm);
    k_btrans <<<1024,         256, 0, stream>>>(cb, bT);
    k_argmin <<<(MTOT / 64) * 2, 512, 0, stream>>>(z, bT, cnorm, anorm, pv, pi);
    k_combine<<<MTOT / 256,   256, 0, stream>>>(pv, pi, idxi, idxf);
    k_gather <<<MTOT / 64,    256, 0, stream>>>(z, cb, idxi, out, lacc);
    k_final  <<<1, 1, 0, stream>>>(lacc, loss_out);
}